// Round 1
// baseline (2460.301 us; speedup 1.0000x reference)
//
#include <hip/hip_runtime.h>
#include <cstdint>
#include <cstddef>

#define NB 64      // batch
#define NN 1000    // nodes
#define NE 16000   // edges

__device__ __forceinline__ float lrelu(float x) { return x > 0.f ? x : 0.01f * x; }

// ---------------- CSR build ----------------
__global__ void k_deg(const int* __restrict__ edges, int* __restrict__ deg) {
    int e = blockIdx.x * 256 + threadIdx.x;
    if (e < NE) {
        atomicAdd(&deg[edges[e]], 1);        // src
        atomicAdd(&deg[edges[NE + e]], 1);   // dst
    }
}

__global__ void k_scan(const int* __restrict__ deg, int* __restrict__ offs) {
    __shared__ int s[1024];
    int t = threadIdx.x;
    s[t] = (t < NN) ? deg[t] : 0;
    __syncthreads();
    for (int d = 1; d < 1024; d <<= 1) {
        int v = (t >= d) ? s[t - d] : 0;
        __syncthreads();
        s[t] += v;
        __syncthreads();
    }
    if (t < NN) offs[t + 1] = s[t];
    if (t == 0) offs[0] = 0;
}

// deterministic fill: incidences sorted by (edge id, src-role-before-dst-role)
__global__ void k_fill(const int* __restrict__ edges, const int* __restrict__ offs,
                       int* __restrict__ adj) {
    int n = blockIdx.x;
    int lane = threadIdx.x;  // 64 threads = 1 wave
    int base = offs[n];
    int run = 0;
    for (int e0 = 0; e0 < NE; e0 += 64) {
        int e = e0 + lane;
        int s = -1, d = -1;
        if (e < NE) { s = edges[e]; d = edges[NE + e]; }
        unsigned long long ms = __ballot(s == n);
        unsigned long long md = __ballot(d == n);
        unsigned long long below = (lane == 63) ? 0x7fffffffffffffffull
                                                : ((1ull << lane) - 1ull);
        if (s == n) {
            int pos = base + run + __popcll(ms & below) + __popcll(md & below);
            adj[pos] = (d << 1);               // n is src; other=dst -> use B[other]
        }
        if (d == n) {
            int pos = base + run + __popcll(ms & (below | (1ull << lane))) + __popcll(md & below);
            adj[pos] = (s << 1) | 1;           // n is dst; other=src -> use A[other]
        }
        run += __popcll(ms) + __popcll(md);
    }
}

// ---------------- pass-0 node prep: vertices -> A,B projections ----------------
__global__ void k_prep0(const float* __restrict__ vert,
                        const float* __restrict__ xW, const float* __restrict__ xb,
                        const float* __restrict__ yW, const float* __restrict__ yb,
                        const float* __restrict__ tW, const float* __restrict__ tb,
                        const float* __restrict__ cW1, const float* __restrict__ cb1,
                        const float* __restrict__ cW2, const float* __restrict__ cb2,
                        const float* __restrict__ vW1, const float* __restrict__ vb1,
                        const float* __restrict__ vW2, const float* __restrict__ vb2,
                        const float* __restrict__ eW1, const float* __restrict__ eb1,
                        float* __restrict__ Ap, float* __restrict__ Bp) {
    int idx = blockIdx.x * blockDim.x + threadIdx.x;  // 64000 threads
    int n = idx >> 6, b = idx & 63;
    const float* vp = vert + ((size_t)b * NN + n) * 11;
    float vv[11];
#pragma unroll
    for (int i = 0; i < 11; i++) vv[i] = vp[i];

    float config[64];
#pragma unroll
    for (int half = 0; half < 2; half++) {
        float f[24];
        const float* o = vv + (half ? 6 : 3);
        {
            const float* Ws[3] = {xW, yW, tW};
            const float* bs[3] = {xb, yb, tb};
#pragma unroll
            for (int i = 0; i < 3; i++) {
                float p0 = vv[i], p1 = o[i];
#pragma unroll
                for (int c = 0; c < 8; c++)
                    f[i * 8 + c] = lrelu(Ws[i][c * 2] * p0 + Ws[i][c * 2 + 1] * p1 + bs[i][c]);
            }
        }
        float h[32];
#pragma unroll
        for (int oc = 0; oc < 32; oc++) {
            float s = cb1[oc];
#pragma unroll
            for (int c = 0; c < 24; c++) s += cW1[oc * 24 + c] * f[c];
            h[oc] = lrelu(s);
        }
#pragma unroll
        for (int oc = 0; oc < 32; oc++) {
            float s = cb2[oc];
#pragma unroll
            for (int c = 0; c < 32; c++) s += cW2[oc * 32 + c] * h[c];
            config[half * 32 + oc] = lrelu(s);
        }
    }
    float v1[32];
#pragma unroll
    for (int oc = 0; oc < 32; oc++) {
        float s = vb1[oc];
#pragma unroll
        for (int c = 0; c < 64; c++) s += vW1[oc * 64 + c] * config[c];
        v1[oc] = lrelu(s);
    }
    float vf[34];
#pragma unroll
    for (int oc = 0; oc < 32; oc++) {
        float s = vb2[oc];
#pragma unroll
        for (int c = 0; c < 32; c++) s += vW2[oc * 32 + c] * v1[c];
        vf[oc] = lrelu(s);
    }
    vf[32] = vv[9]; vf[33] = vv[10];

    size_t outb = ((size_t)n * NB + b) * 32;
#pragma unroll
    for (int oc = 0; oc < 32; oc++) {
        float sa = eb1[oc], sb = 0.f;
#pragma unroll
        for (int c = 0; c < 34; c++) {
            sa += eW1[oc * 68 + c] * vf[c];
            sb += eW1[oc * 68 + 34 + c] * vf[c];
        }
        Ap[outb + oc] = sa;
        Bp[outb + oc] = sb;
    }
}

// ---------------- per-iteration node prep: nv -> h -> A,B ----------------
__global__ void k_prep(const float* __restrict__ nv, const float* __restrict__ vert,
                       const float* __restrict__ aW1, const float* __restrict__ ab1,
                       const float* __restrict__ aW2, const float* __restrict__ ab2,
                       const float* __restrict__ eW1, const float* __restrict__ eb1,
                       float* __restrict__ Ap, float* __restrict__ Bp) {
    int idx = blockIdx.x * blockDim.x + threadIdx.x;
    int n = idx >> 6, b = idx & 63;
    const float* xp = nv + ((size_t)n * NB + b) * 32;
    float x[32];
#pragma unroll
    for (int c = 0; c < 32; c++) x[c] = xp[c];
    float h[32];
#pragma unroll
    for (int oc = 0; oc < 32; oc++) {
        float s = ab1[oc];
#pragma unroll
        for (int c = 0; c < 32; c++) s += aW1[oc * 32 + c] * x[c];
        h[oc] = lrelu(s);
    }
    float vf[34];
#pragma unroll
    for (int oc = 0; oc < 32; oc++) {
        float s = ab2[oc];
#pragma unroll
        for (int c = 0; c < 32; c++) s += aW2[oc * 32 + c] * h[c];
        vf[oc] = lrelu(s);
    }
    const float* vp = vert + ((size_t)b * NN + n) * 11;
    vf[32] = vp[9]; vf[33] = vp[10];

    size_t outb = ((size_t)n * NB + b) * 32;
#pragma unroll
    for (int oc = 0; oc < 32; oc++) {
        float sa = eb1[oc], sb = 0.f;
#pragma unroll
        for (int c = 0; c < 34; c++) {
            sa += eW1[oc * 68 + c] * vf[c];
            sb += eW1[oc * 68 + 34 + c] * vf[c];
        }
        Ap[outb + oc] = sa;
        Bp[outb + oc] = sb;
    }
}

// ---------------- edge pass: node-centric message accumulate ----------------
__global__ __launch_bounds__(256) void k_edge(
    const float* __restrict__ Ap, const float* __restrict__ Bp,
    const int* __restrict__ offs, const int* __restrict__ adj,
    const float* __restrict__ W2, const float* __restrict__ b2,
    float* __restrict__ nv, int pass0) {
    __shared__ float red[4][64 * 33];
    int n = blockIdx.x;
    int w = threadIdx.x >> 6;     // wave id 0..3
    int lane = threadIdx.x & 63;  // = batch b

    int off0 = offs[n], off1 = offs[n + 1];
    int deg = off1 - off0;

    float baseA[32], baseB[32];
    {
        const float* ap = Ap + ((size_t)n * NB + lane) * 32;
        const float* bp = Bp + ((size_t)n * NB + lane) * 32;
#pragma unroll
        for (int c = 0; c < 32; c++) { baseA[c] = ap[c]; baseB[c] = bp[c]; }
    }
    float acc[32];
#pragma unroll
    for (int c = 0; c < 32; c++) acc[c] = 0.f;

    for (int p = off0 + w; p < off1; p += 4) {
        int a = adj[p];               // uniform across wave
        int other = a >> 1;
        int role = a & 1;             // 1: n is dst -> other uses A; 0: n is src -> other uses B
        const float* og = (role ? Ap : Bp) + ((size_t)other * NB + lane) * 32;
        float h1[32];
        if (role) {
#pragma unroll
            for (int c = 0; c < 32; c++) h1[c] = lrelu(baseB[c] + og[c]);
        } else {
#pragma unroll
            for (int c = 0; c < 32; c++) h1[c] = lrelu(baseA[c] + og[c]);
        }
#pragma unroll
        for (int oc = 0; oc < 32; oc++) {
            float s = b2[oc];
#pragma unroll
            for (int k = 0; k < 32; k++) s += W2[oc * 32 + k] * h1[k];
            acc[oc] += lrelu(s);
        }
    }

    // cross-wave reduce via LDS (padded rows: bank-conflict-free)
#pragma unroll
    for (int c = 0; c < 32; c++) red[w][lane * 33 + c] = acc[c];
    __syncthreads();

    int t = threadIdx.x;
    size_t nb = (size_t)n * (NB * 32);
    if (deg > 0) {
        float inv = 1.f / (float)deg;
#pragma unroll
        for (int j = 0; j < 8; j++) {
            int idx = t * 8 + j;
            int bb = idx >> 5, cc = idx & 31;
            float s = red[0][bb * 33 + cc] + red[1][bb * 33 + cc] +
                      red[2][bb * 33 + cc] + red[3][bb * 33 + cc];
            s *= inv;
            if (!pass0) s += nv[nb + idx];
            nv[nb + idx] = s;
        }
    } else if (pass0) {
#pragma unroll
        for (int j = 0; j < 8; j++) nv[nb + t * 8 + j] = 0.f;
    }
}

// ---------------- final readout ----------------
__global__ void k_final(const float* __restrict__ nv,
                        const float* __restrict__ oW1, const float* __restrict__ ob1,
                        const float* __restrict__ oW2, const float* __restrict__ ob2,
                        const float* __restrict__ gW, const float* __restrict__ gb,
                        float* __restrict__ out) {
    int b = blockIdx.x;
    int t = threadIdx.x;  // 256
    float part = 0.f;
    for (int n = t; n < NN; n += 256) {
        const float* xp = nv + ((size_t)n * NB + b) * 32;
        float x[32];
#pragma unroll
        for (int c = 0; c < 32; c++) x[c] = xp[c];
        float h[32];
#pragma unroll
        for (int oc = 0; oc < 32; oc++) {
            float s = ob1[oc];
#pragma unroll
            for (int c = 0; c < 32; c++) s += oW1[oc * 32 + c] * x[c];
            h[oc] = lrelu(s);
        }
        float s = ob2[0];
#pragma unroll
        for (int k = 0; k < 32; k++) s += oW2[k] * h[k];
        part += lrelu(s) * gW[n];
    }
    __shared__ float rs[256];
    rs[t] = part;
    __syncthreads();
    for (int d = 128; d > 0; d >>= 1) {
        if (t < d) rs[t] += rs[t + d];
        __syncthreads();
    }
    if (t == 0) out[b] = 1.f / (1.f + expf(-(rs[0] + gb[0])));
}

extern "C" void kernel_launch(void* const* d_in, const int* in_sizes, int n_in,
                              void* d_out, int out_size, void* d_ws, size_t ws_size,
                              hipStream_t stream) {
    (void)in_sizes; (void)n_in; (void)out_size; (void)ws_size;
    const float* vert = (const float*)d_in[0];
    const int* edges  = (const int*)d_in[1];
    const float* xW   = (const float*)d_in[2];
    const float* xb   = (const float*)d_in[3];
    const float* yW   = (const float*)d_in[4];
    const float* yb   = (const float*)d_in[5];
    const float* tW   = (const float*)d_in[6];
    const float* tb   = (const float*)d_in[7];
    const float* cW1  = (const float*)d_in[8];
    const float* cb1  = (const float*)d_in[9];
    const float* cW2  = (const float*)d_in[10];
    const float* cb2  = (const float*)d_in[11];
    const float* vW1  = (const float*)d_in[12];
    const float* vb1  = (const float*)d_in[13];
    const float* vW2  = (const float*)d_in[14];
    const float* vb2  = (const float*)d_in[15];
    const float* eW1  = (const float*)d_in[16];
    const float* eb1  = (const float*)d_in[17];
    const float* eW2  = (const float*)d_in[18];
    const float* eb2  = (const float*)d_in[19];
    const float* aW1  = (const float*)d_in[20];
    const float* ab1  = (const float*)d_in[21];
    const float* aW2  = (const float*)d_in[22];
    const float* ab2  = (const float*)d_in[23];
    const float* oW1  = (const float*)d_in[24];
    const float* ob1  = (const float*)d_in[25];
    const float* oW2  = (const float*)d_in[26];
    const float* ob2  = (const float*)d_in[27];
    const float* gW   = (const float*)d_in[28];
    const float* gb   = (const float*)d_in[29];
    float* out = (float*)d_out;

    char* w = (char*)d_ws;
    float* Ap = (float*)(w);
    float* Bp = (float*)(w + 8u * 1024 * 1024);
    float* nv = (float*)(w + 16u * 1024 * 1024);
    int* deg  = (int*)(w + 24u * 1024 * 1024);
    int* offs = deg + 1024;
    int* adj  = offs + 1024;

    hipMemsetAsync(deg, 0, NN * sizeof(int), stream);
    k_deg<<<(NE + 255) / 256, 256, 0, stream>>>(edges, deg);
    k_scan<<<1, 1024, 0, stream>>>(deg, offs);
    k_fill<<<NN, 64, 0, stream>>>(edges, offs, adj);

    k_prep0<<<(NB * NN) / 256, 256, 0, stream>>>(vert, xW, xb, yW, yb, tW, tb,
                                                 cW1, cb1, cW2, cb2, vW1, vb1, vW2, vb2,
                                                 eW1, eb1, Ap, Bp);
    k_edge<<<NN, 256, 0, stream>>>(Ap, Bp, offs, adj, eW2, eb2, nv, 1);

    for (int it = 0; it < 5; it++) {
        k_prep<<<(NB * NN) / 256, 256, 0, stream>>>(nv, vert, aW1, ab1, aW2, ab2,
                                                    eW1, eb1, Ap, Bp);
        k_edge<<<NN, 256, 0, stream>>>(Ap, Bp, offs, adj, eW2, eb2, nv, 0);
    }

    k_final<<<NB, 256, 0, stream>>>(nv, oW1, ob1, oW2, ob2, gW, gb, out);
}